// Round 10
// baseline (232.649 us; speedup 1.0000x reference)
//
#include <hip/hip_runtime.h>

// Problem constants
#define B_   2
#define S_   2048
#define H_   2048
#define NH_  16
#define G_   4
#define HD_  128
#define KV_  512
#define HQKV 3072   // fused Q|K|V output width

typedef __attribute__((ext_vector_type(8))) short bf16x8;
typedef __attribute__((ext_vector_type(4))) float f32x4;

__device__ __forceinline__ unsigned short f2bf(float f) {
    unsigned u = __float_as_uint(f);
    u += 0x7fff + ((u >> 16) & 1);   // RNE
    return (unsigned short)(u >> 16);
}
__device__ __forceinline__ float bf2f(unsigned short s) {
    return __uint_as_float(((unsigned)s) << 16);
}
// D.lo = bf16(a), D.hi = bf16(b)  (RNE)
__device__ __forceinline__ unsigned cvtpk(float a, float b) {
    unsigned r;
    asm volatile("v_cvt_pk_bf16_f32 %0, %1, %2" : "=v"(r) : "v"(a), "v"(b));
    return r;
}

#define GLDS16(gsrc, ldst)                                                            \
    __builtin_amdgcn_global_load_lds(                                                 \
        (const __attribute__((address_space(1))) void*)(gsrc),                        \
        (__attribute__((address_space(3))) void*)(ldst), 16, 0, 0)

// 1/sqrt(128) * log2(e): folded into Q columns of the QKV GEMM epilogue
#define SC2F (0.08838834764831843f * 1.4426950408889634f)

// ---------------- fp32 -> bf16 elementwise ----------------
__global__ void k_cvt_bf16(const float* __restrict__ in, unsigned short* __restrict__ out, int n4) {
    int i = blockIdx.x * blockDim.x + threadIdx.x;
    if (i >= n4) return;
    float4 v = ((const float4*)in)[i];
    ushort4 o;
    o.x = f2bf(v.x); o.y = f2bf(v.y); o.z = f2bf(v.z); o.w = f2bf(v.w);
    ((ushort4*)out)[i] = o;
}

// ---------------- fp32 [R][C] -> bf16 [C][R] (weight transpose+convert) ----------------
__global__ void k_transpose_cvt(const float* __restrict__ in, unsigned short* __restrict__ out,
                                int R, int C) {
    __shared__ float t[32][33];
    int c0 = blockIdx.x * 32, r0 = blockIdx.y * 32;
    int tx = threadIdx.x, ty = threadIdx.y;   // 32 x 8
#pragma unroll
    for (int i = 0; i < 4; ++i)
        t[ty + i*8][tx] = in[(size_t)(r0 + ty + i*8) * C + c0 + tx];
    __syncthreads();
#pragma unroll
    for (int i = 0; i < 4; ++i)
        out[(size_t)(c0 + ty + i*8) * R + r0 + tx] = f2bf(t[tx][ty + i*8]);
}

// ---------------- fused Wq|Wk|Wv transpose+convert -> WqkvT [3072][2048] ----------------
__global__ void k_transpose_qkv(const float* __restrict__ Wq, const float* __restrict__ Wk,
                                const float* __restrict__ Wv, unsigned short* __restrict__ out) {
    __shared__ float t[32][33];
    int n0g = blockIdx.x * 32;               // output row block (0..3071)
    int h0 = blockIdx.y * 32;                // input row block (0..2047)
    const float* src; int C, n0l;
    if (n0g < H_)            { src = Wq; C = H_;  n0l = n0g; }
    else if (n0g < H_ + KV_) { src = Wk; C = KV_; n0l = n0g - H_; }
    else                     { src = Wv; C = KV_; n0l = n0g - H_ - KV_; }
    int tx = threadIdx.x, ty = threadIdx.y;  // 32 x 8
#pragma unroll
    for (int i = 0; i < 4; ++i)
        t[ty + i*8][tx] = src[(size_t)(h0 + ty + i*8) * C + n0l + tx];
    __syncthreads();
#pragma unroll
    for (int i = 0; i < 4; ++i)
        out[(size_t)(n0g + ty + i*8) * H_ + h0 + tx] = f2bf(t[tx][ty + i*8]);
}

// ---------------- concat bq|bk|bv -> [3072] ----------------
__global__ void k_concat_bias(const float* __restrict__ bq, const float* __restrict__ bk,
                              const float* __restrict__ bv, float* __restrict__ out) {
    int i = blockIdx.x * 256 + threadIdx.x;
    if (i >= HQKV) return;
    out[i] = (i < H_) ? bq[i] : (i < H_ + KV_ ? bk[i - H_] : bv[i - H_ - KV_]);
}

// ---------------- V slice of QKV [B*S][3072] -> V^T [B][KV][S] ----------------
__global__ void k_transpose_v(const unsigned short* __restrict__ in, unsigned short* __restrict__ out) {
    __shared__ unsigned short t[32][33];
    int b = blockIdx.z;
    int c0 = blockIdx.x * 32, s0 = blockIdx.y * 32;
    int tx = threadIdx.x, ty = threadIdx.y;
#pragma unroll
    for (int i = 0; i < 4; ++i)
        t[ty + i*8][tx] = in[((size_t)b * S_ + s0 + ty + i*8) * HQKV + (H_ + KV_) + c0 + tx];
    __syncthreads();
#pragma unroll
    for (int i = 0; i < 4; ++i)
        out[((size_t)b * KV_ + c0 + ty + i*8) * S_ + s0 + tx] = t[tx][ty + i*8];
}

// ---------------- 256x256 8-phase bf16 GEMM (validated R9) ----------------
template <bool BF16OUT, bool QSCALE>
__global__ __launch_bounds__(512, 2) void k_gemm256(
    const unsigned short* __restrict__ A, const unsigned short* __restrict__ Bt,
    const float* __restrict__ bias, void* __restrict__ Cout, int M, int N, int K) {
    __shared__ __align__(16) unsigned short As[2][256 * 64];
    __shared__ __align__(16) unsigned short Bs[2][256 * 64];
    const int tid = threadIdx.x, lane = tid & 63;
    const int w = tid >> 6;
    const int l15 = lane & 15, l4 = lane >> 4;
    const int wr = w >> 2, wc = w & 3;        // 2 x 4 wave grid
    const int m0 = blockIdx.x * 256, n0 = blockIdx.y * 256;
    f32x4 acc[8][4] = {};

    auto stageA = [&](int buf, int kt, int h) {
#pragma unroll
        for (int i = 0; i < 2; ++i) {
            int p = i * 512 + tid;
            int j = p >> 3;
            int row = h * 64 + (j >> 6) * 128 + (j & 63);
            int sc = p & 7;
            int c = sc ^ (row & 7);
            GLDS16(A + (size_t)(m0 + row) * K + kt * 64 + c * 8,
                   &As[buf][(row * 8 + sc) * 8]);
        }
    };
    auto stageB = [&](int buf, int kt, int h) {
#pragma unroll
        for (int i = 0; i < 2; ++i) {
            int p = i * 512 + tid;
            int j = p >> 3;
            int row = h * 32 + (j >> 5) * 64 + (j & 31);
            int sc = p & 7;
            int c = sc ^ (row & 7);
            GLDS16(Bt + (size_t)(n0 + row) * K + kt * 64 + c * 8,
                   &Bs[buf][(row * 8 + sc) * 8]);
        }
    };

    const int NT = K >> 6;
    stageB(0, 0, 0); stageA(0, 0, 0); stageB(0, 0, 1); stageA(0, 0, 1);
    stageB(1, 1, 0); stageA(1, 1, 0);

    bf16x8 bf[2][2];
    for (int t = 0; t < NT; ++t) {
        const int cur = t & 1, nxt = cur ^ 1;
        if (t == NT - 1) { asm volatile("s_waitcnt vmcnt(0)" ::: "memory"); }
        else             { asm volatile("s_waitcnt vmcnt(4)" ::: "memory"); }
        __builtin_amdgcn_s_barrier();
        __builtin_amdgcn_sched_barrier(0);

#pragma unroll
        for (int q = 0; q < 4; ++q) {
            const int nh = q >> 1, mh = q & 1;
            bf16x8 af[4][2];
#pragma unroll
            for (int mf2 = 0; mf2 < 4; ++mf2)
#pragma unroll
                for (int ks = 0; ks < 2; ++ks) {
                    int row = wr * 128 + (mh * 4 + mf2) * 16 + l15;
                    int ch = (ks * 4 + l4) ^ (row & 7);
                    af[mf2][ks] = *(const bf16x8*)(&As[cur][(row * 8 + ch) * 8]);
                }
            if (mh == 0) {
#pragma unroll
                for (int nf2 = 0; nf2 < 2; ++nf2)
#pragma unroll
                    for (int ks = 0; ks < 2; ++ks) {
                        int row = wc * 64 + (nh * 2 + nf2) * 16 + l15;
                        int ch = (ks * 4 + l4) ^ (row & 7);
                        bf[nf2][ks] = *(const bf16x8*)(&Bs[cur][(row * 8 + ch) * 8]);
                    }
            }
            if (q == 0)      { if (t + 1 < NT) stageB(nxt, t + 1, 1); }
            else if (q == 1) { if (t + 1 < NT) stageA(nxt, t + 1, 1); }
            else if (q == 2) { if (t + 2 < NT) stageB(cur, t + 2, 0); }
            else             { if (t + 2 < NT) stageA(cur, t + 2, 0); }

            __builtin_amdgcn_sched_barrier(0);
            __builtin_amdgcn_s_barrier();
            asm volatile("s_waitcnt lgkmcnt(0)" ::: "memory");
            __builtin_amdgcn_sched_barrier(0);
            __builtin_amdgcn_s_setprio(1);
#pragma unroll
            for (int mf2 = 0; mf2 < 4; ++mf2)
#pragma unroll
                for (int nf2 = 0; nf2 < 2; ++nf2)
#pragma unroll
                    for (int ks = 0; ks < 2; ++ks)
                        acc[mh * 4 + mf2][nh * 2 + nf2] = __builtin_amdgcn_mfma_f32_16x16x32_bf16(
                            af[mf2][ks], bf[nf2][ks], acc[mh * 4 + mf2][nh * 2 + nf2], 0, 0, 0);
            __builtin_amdgcn_s_setprio(0);
            __builtin_amdgcn_s_barrier();
        }
    }

#pragma unroll
    for (int mf = 0; mf < 8; ++mf) {
        int row = m0 + wr * 128 + mf * 16 + l4 * 4;
#pragma unroll
        for (int nf = 0; nf < 4; ++nf) {
            int col = n0 + wc * 64 + nf * 16 + l15;
            float bv = bias[col];
#pragma unroll
            for (int r = 0; r < 4; ++r) {
                float v = acc[mf][nf][r] + bv;
                if (QSCALE) { if (col < H_) v *= SC2F; }
                if (BF16OUT)
                    ((unsigned short*)Cout)[(size_t)(row + r) * N + col] = f2bf(v);
                else
                    ((float*)Cout)[(size_t)(row + r) * N + col] = v;
            }
        }
    }
}

// ---------------- pipelined 128x128 GEMM (R8-validated pipeline, 2D grid) ----------------
template <bool BF16OUT, bool QSCALE>
__global__ __launch_bounds__(256) void k_gemm128p(
    const unsigned short* __restrict__ A, const unsigned short* __restrict__ Bt,
    const float* __restrict__ bias, void* __restrict__ Cout, int M, int N, int K) {
    __shared__ __align__(16) unsigned short As[2][128 * 64];
    __shared__ __align__(16) unsigned short Bs[2][128 * 64];
    const int tid = threadIdx.x, lane = tid & 63, w = tid >> 6;
    const int l15 = lane & 15, l4 = lane >> 4;
    const int wr = w >> 1, wc = w & 1;
    const int m0 = blockIdx.x * 128, n0 = blockIdx.y * 128;
    f32x4 acc[4][4] = {};

    auto stage = [&](int buf, int kt) {
#pragma unroll
        for (int i = 0; i < 4; ++i) {
            int p = (w * 4 + i) * 64 + lane;
            int row = p >> 3, c = (p & 7) ^ (row & 7);
            GLDS16(A + (size_t)(m0 + row) * K + kt * 64 + c * 8, &As[buf][(w * 4 + i) * 512]);
        }
#pragma unroll
        for (int i = 0; i < 4; ++i) {
            int p = (w * 4 + i) * 64 + lane;
            int row = p >> 3, c = (p & 7) ^ (row & 7);
            GLDS16(Bt + (size_t)(n0 + row) * K + kt * 64 + c * 8, &Bs[buf][(w * 4 + i) * 512]);
        }
    };

    const int NT = K >> 6;
    stage(0, 0);
    if (NT > 1) stage(1, 1);

    for (int t = 0; t < NT; ++t) {
        const int cur = t & 1;
        if (t + 1 < NT) { asm volatile("s_waitcnt vmcnt(8)" ::: "memory"); }
        else            { asm volatile("s_waitcnt vmcnt(0)" ::: "memory"); }
        __builtin_amdgcn_s_barrier();
        __builtin_amdgcn_sched_barrier(0);

        bf16x8 bfr[2][4];
#pragma unroll
        for (int ks = 0; ks < 2; ++ks)
#pragma unroll
            for (int n = 0; n < 4; ++n) {
                int row = wc * 64 + n * 16 + l15;
                int sl = (ks * 4 + l4) ^ (row & 7);
                bfr[ks][n] = *(const bf16x8*)(&Bs[cur][(row * 8 + sl) * 8]);
            }
#pragma unroll
        for (int fr = 0; fr < 4; ++fr) {
            int row = wr * 64 + fr * 16 + l15;
            bf16x8 af0 = *(const bf16x8*)(&As[cur][(row * 8 + (l4 ^ (row & 7))) * 8]);
            bf16x8 af1 = *(const bf16x8*)(&As[cur][(row * 8 + ((4 + l4) ^ (row & 7))) * 8]);
            __builtin_amdgcn_s_setprio(1);
#pragma unroll
            for (int n = 0; n < 4; ++n)
                acc[fr][n] = __builtin_amdgcn_mfma_f32_16x16x32_bf16(af0, bfr[0][n], acc[fr][n], 0, 0, 0);
#pragma unroll
            for (int n = 0; n < 4; ++n)
                acc[fr][n] = __builtin_amdgcn_mfma_f32_16x16x32_bf16(af1, bfr[1][n], acc[fr][n], 0, 0, 0);
            __builtin_amdgcn_s_setprio(0);
        }

        __builtin_amdgcn_s_barrier();
        __builtin_amdgcn_sched_barrier(0);
        if (t + 2 < NT) stage(cur, t + 2);
    }

#pragma unroll
    for (int fr = 0; fr < 4; ++fr) {
        int row = m0 + wr * 64 + fr * 16 + l4 * 4;
#pragma unroll
        for (int n = 0; n < 4; ++n) {
            int col = n0 + wc * 64 + n * 16 + l15;
            float bv = bias[col];
#pragma unroll
            for (int r = 0; r < 4; ++r) {
                float v = acc[fr][n][r] + bv;
                if (QSCALE) { if (col < H_) v *= SC2F; }
                if (BF16OUT)
                    ((unsigned short*)Cout)[(size_t)(row + r) * N + col] = f2bf(v);
                else
                    ((float*)Cout)[(size_t)(row + r) * N + col] = v;
            }
        }
    }
}

// ---------------- causal GQA flash attention: QBLK=128, swapped-QK, in-reg softmax ----------------
// 4 waves x 32 q-rows (two 16-col groups per wave). K/V tiles shared across 128 q-rows:
// per-MFMA staging/barrier/ds_read overhead halves vs QBLK=64. Split-K at 16 k-tiles.
// Jobs per bh: 8 chunk0 (16t) + pairs {chunk1 qt=15-j (16-2j t), full qt=7-j (16-2j t)}.
__global__ __launch_bounds__(256, 3) void k_flash(
    const unsigned short* __restrict__ QKV,  // [B*S][3072]  Q|K|V  (Q pre-scaled)
    const unsigned short* __restrict__ VT,   // [B][KV][S]
    unsigned short* __restrict__ Oa,         // [B*S][H]
    unsigned short* __restrict__ part1,      // [256][128][128] bf16 chunk1 partial O
    float* __restrict__ mlbuf) {             // [512][128][2] f32 (m,l) per chunk
    __shared__ __align__(16) unsigned short Ks[64 * 128];    // K tile, chunk-swizzled
    __shared__ __align__(16) unsigned short Vs[128 * 64];    // V^T tile, chunk-swizzled
    const int tid = threadIdx.x, lane = tid & 63, w = tid >> 6;
    const int l15 = lane & 15, l4 = lane >> 4;
    const int bid = blockIdx.x;               // 0..767
    const int xcd = bid & 7, idx = bid >> 3;  // 96 jobs per XCD
    const int bh = xcd * 4 + (idx & 3);       // 4 heads per XCD = one (b,g)
    const int jidx = idx >> 2;                // 0..23, descending work
    const int b = bh >> 4, nh = bh & 15, g = nh >> 2;

    int qt, t0, t1, mode;                     // mode: 0 full, 1 chunk0, 2 chunk1
    if (jidx < 8) { qt = 8 + jidx; t0 = 0; t1 = 16; mode = 1; }
    else {
        int k = jidx - 8, j = k >> 1;
        if ((k & 1) == 0) { qt = 15 - j; t0 = 16; t1 = 2 * qt + 2; mode = 2; }
        else              { qt = 7 - j;  t0 = 0;  t1 = 2 * qt + 2; mode = 0; }
    }
    const int qbase = qt * 128 + w * 32;      // wave's 32 q-rows; group g2: q = qbase+g2*16+l15

    const unsigned short* kgbase = QKV + (size_t)b * S_ * HQKV + H_ + g * HD_;
    const unsigned short* vgbase = VT + ((size_t)b * KV_ + g * HD_) * S_;

    auto issueK = [&](int kt) {
        const int kv0 = kt * 64;
#pragma unroll
        for (int i = 0; i < 4; ++i) {
            int p = i * 256 + tid;
            int row = p >> 4, c = (p & 15) ^ (row & 15);
            GLDS16(kgbase + (size_t)(kv0 + row) * HQKV + c * 8, &Ks[(i * 256 + w * 64) * 8]);
        }
    };
    auto issueV = [&](int kt) {
        const int kv0 = kt * 64;
#pragma unroll
        for (int i = 0; i < 4; ++i) {
            int p = i * 256 + tid;
            int row = p >> 3, c = (p & 7) ^ (row & 7);
            GLDS16(vgbase + (size_t)row * S_ + kv0 + c * 8, &Vs[(i * 256 + w * 64) * 8]);
        }
    };

    // Q fragments (pre-scaled), two groups
    bf16x8 qf[2][4];
#pragma unroll
    for (int g2 = 0; g2 < 2; ++g2)
#pragma unroll
        for (int kb = 0; kb < 4; ++kb)
            qf[g2][kb] = *(const bf16x8*)(QKV + (size_t)(b * S_ + qbase + g2 * 16 + l15) * HQKV +
                                          nh * HD_ + kb * 32 + l4 * 8);

    f32x4 o[2][8] = {};                       // O^T per group
    float m_r[2] = {-1e30f, -1e30f}, l_r[2] = {0.f, 0.f};

    const int src0 = l15 + 16 * ((2 * l4) & 3);
    const int src1 = l15 + 16 * ((2 * l4 + 1) & 3);
    const bool hsel = ((l4 >> 1) & 1) != 0;

    issueK(t0);
    issueV(t0);

    for (int kt = t0; kt < t1; ++kt) {
        const int kv0 = kt * 64;
        asm volatile("s_waitcnt vmcnt(4)" ::: "memory");
        __builtin_amdgcn_s_barrier();
        __builtin_amdgcn_sched_barrier(0);

        // S^T = K Q^T for both q-groups (kf shared)
        f32x4 s[2][4] = {};
#pragma unroll
        for (int kb = 0; kb < 4; ++kb) {
            bf16x8 kf[4];
#pragma unroll
            for (int n = 0; n < 4; ++n) {
                int row = n * 16 + l15;
                int sl = (kb * 4 + l4) ^ (row & 15);
                kf[n] = *(const bf16x8*)(&Ks[(row * 16 + sl) * 8]);
            }
            __builtin_amdgcn_s_setprio(1);
#pragma unroll
            for (int g2 = 0; g2 < 2; ++g2)
#pragma unroll
                for (int n = 0; n < 4; ++n)
                    s[g2][n] = __builtin_amdgcn_mfma_f32_16x16x32_bf16(kf[n], qf[g2][kb], s[g2][n], 0, 0, 0);
            __builtin_amdgcn_s_setprio(0);
        }
        // causal mask (only in diagonal region of this wave's 32 rows)
        if (kv0 + 63 > qbase) {
#pragma unroll
            for (int g2 = 0; g2 < 2; ++g2) {
                const int qrow = qbase + g2 * 16 + l15;
#pragma unroll
                for (int n = 0; n < 4; ++n)
#pragma unroll
                    for (int r = 0; r < 4; ++r) {
                        int kcol = kv0 + n * 16 + l4 * 4 + r;
                        if (kcol > qrow) s[g2][n][r] = -1e30f;
                    }
            }
        }
        // per-lane softmax per group + defer-max
        unsigned plo[2][4], phi[2][4];
#pragma unroll
        for (int g2 = 0; g2 < 2; ++g2) {
            float pmax = s[g2][0][0];
#pragma unroll
            for (int n = 0; n < 4; ++n)
#pragma unroll
                for (int r = 0; r < 4; ++r) pmax = fmaxf(pmax, s[g2][n][r]);
            pmax = fmaxf(pmax, __shfl_xor(pmax, 16));
            pmax = fmaxf(pmax, __shfl_xor(pmax, 32));
            if (__any(pmax > m_r[g2] + 8.0f)) {
                float mn = fmaxf(m_r[g2], pmax);
                float sf = exp2f(m_r[g2] - mn);
                m_r[g2] = mn;
                l_r[g2] *= sf;
#pragma unroll
                for (int nc = 0; nc < 8; ++nc) {
                    f32x4 t = o[g2][nc];
                    t[0] *= sf; t[1] *= sf; t[2] *= sf; t[3] *= sf;
                    o[g2][nc] = t;
                }
            }
            float rsum = 0.f;
#pragma unroll
            for (int n = 0; n < 4; ++n)
#pragma unroll
                for (int r = 0; r < 4; ++r) {
                    float p = exp2f(s[g2][n][r] - m_r[g2]);
                    s[g2][n][r] = p;
                    rsum += p;
                }
            rsum += __shfl_xor(rsum, 16);
            rsum += __shfl_xor(rsum, 32);
            l_r[g2] += rsum;
#pragma unroll
            for (int n = 0; n < 4; ++n) {
                plo[g2][n] = cvtpk(s[g2][n][0], s[g2][n][1]);
                phi[g2][n] = cvtpk(s[g2][n][2], s[g2][n][3]);
            }
        }

        asm volatile("s_waitcnt vmcnt(0)" ::: "memory");
        __builtin_amdgcn_s_barrier();
        __builtin_amdgcn_sched_barrier(0);
        if (kt + 1 < t1) issueK(kt + 1);

        // O^T += V^T P^T; vf shared across groups
#pragma unroll
        for (int kb = 0; kb < 2; ++kb) {
            const int n0i = 2 * kb, n1i = 2 * kb + 1;
            bf16x8 pf[2];
#pragma unroll
            for (int g2 = 0; g2 < 2; ++g2) {
                unsigned a0, a1, w0, w1, w2, w3;
                a0 = __shfl((int)plo[g2][n0i], src0); a1 = __shfl((int)plo[g2][n1i], src0); w0 = hsel ? a1 : a0;
                a0 = __shfl((int)phi[g2][n0i], src0); a1 = __shfl((int)phi[g2][n1i], src0); w1 = hsel ? a1 : a0;
                a0 = __shfl((int)plo[g2][n0i], src1); a1 = __shfl((int)plo[g2][n1i], src1); w2 = hsel ? a1 : a0;
                a0 = __shfl((int)phi[g2][n0i], src1); a1 = __shfl((int)phi[g2][n1i], src1); w3 = hsel ? a1 : a0;
                int4 pw = make_int4((int)w0, (int)w1, (int)w2, (int)w3);
                pf[g2] = *(bf16x8*)&pw;
            }
            __builtin_amdgcn_s_setprio(1);
#pragma unroll
            for (int nc = 0; nc < 8; ++nc) {
                int row = nc * 16 + l15;
                int sl = (kb * 4 + l4) ^ (row & 7);
                bf16x8 vf = *(const bf16x8*)(&Vs[(row * 8 + sl) * 8]);
                o[0][nc] = __builtin_amdgcn_mfma_f32_16x16x32_bf16(vf, pf[0], o[0][nc], 0, 0, 0);
                o[1][nc] = __builtin_amdgcn_mfma_f32_16x16x32_bf16(vf, pf[1], o[1][nc], 0, 0, 0);
            }
            __builtin_amdgcn_s_setprio(0);
        }

        __builtin_amdgcn_s_barrier();
        __builtin_amdgcn_sched_barrier(0);
        if (kt + 1 < t1) issueV(kt + 1);
    }

    // epilogue per group
    if (mode == 0) {
#pragma unroll
        for (int g2 = 0; g2 < 2; ++g2) {
            float inv = 1.0f / l_r[g2];
            int qrow = qbase + g2 * 16 + l15;
            size_t base = (size_t)(b * S_ + qrow) * H_ + nh * HD_ + l4 * 4;
#pragma unroll
            for (int nc = 0; nc < 8; ++nc) {
                uint2 pk;
                pk.x = cvtpk(o[g2][nc][0] * inv, o[g2][nc][1] * inv);
                pk.y = cvtpk(o[g2][nc][2] * inv, o[g2][nc][3] * inv);
                *(uint2*)(Oa + base + nc * 16) = pk;
            }
        }
    } else {
        const int base = bh * 8 + (qt - 8);
        const int c = (mode == 1) ? 0 : 1;
        float* mlrec = mlbuf + (size_t)(base * 2 + c) * 256;   // [128][2]
        if (l4 == 0) {
#pragma unroll
            for (int g2 = 0; g2 < 2; ++g2) {
                int row = w * 32 + g2 * 16 + l15;
                mlrec[row * 2 + 0] = m_r[g2];
                mlrec[row * 2 + 1] = l_r[g2];
            }
        }
        if (mode == 1) {
#pragma unroll
            for (int g2 = 0; g2 < 2; ++g2) {
                int qrow = qbase + g2 * 16 + l15;
                size_t ob = (size_t)(b * S_ + qrow) * H_ + nh * HD_ + l4 * 4;
#pragma unroll
                for (int nc = 0; nc < 8; ++nc) {
                    uint2 pk;
                    pk.x = cvtpk(o[g2][nc][0], o[g2][nc][1]);
                    pk.y = cvtpk(o[g2][nc][2], o[g2][nc][3]);
                    *(uint2*)(Oa + ob + nc * 16) = pk;
                }
            }
        } else {
#pragma unroll
            for (int g2 = 0; g2 < 2; ++g2) {
                size_t pb = ((size_t)base * 128 + w * 32 + g2 * 16 + l15) * 128 + l4 * 4;
#pragma unroll
                for (int nc = 0; nc < 8; ++nc) {
                    uint2 pk;
                    pk.x = cvtpk(o[g2][nc][0], o[g2][nc][1]);
                    pk.y = cvtpk(o[g2][nc][2], o[g2][nc][3]);
                    *(uint2*)(part1 + pb + nc * 16) = pk;
                }
            }
        }
    }
}

// ---------------- combine split-K partials ----------------
__global__ __launch_bounds__(256) void k_combine(
    const float* __restrict__ mlbuf, const unsigned short* __restrict__ part1,
    unsigned short* __restrict__ Oa) {
    int rec = blockIdx.x;                 // 0..255: bh*8 + (qt-8)
    int bh = rec >> 3, qt = 8 + (rec & 7);
    int b = bh >> 4, nh = bh & 15;
    int row = threadIdx.x >> 1;           // 0..127
    int dseg = (threadIdx.x & 1) * 64;
    const float* ml0 = mlbuf + (size_t)(rec * 2 + 0) * 256;
    const float* ml1 = mlbuf + (size_t)(rec * 2 + 1) * 256;
    float m0 = ml0[row * 2], l0 = ml0[row * 2 + 1];
    float m1 = ml1[row * 2], l1 = ml1[row * 2 + 1];
    float M = fmaxf(m0, m1);
    float a0 = exp2f(m0 - M), a1 = exp2f(m1 - M);
    float L = a0 * l0 + a1 * l1;
    float s0 = a0 / L, s1 = a1 / L;
    size_t ob = ((size_t)(b * S_) + qt * 128 + row) * H_ + nh * HD_ + dseg;
    const unsigned short* p1 = part1 + ((size_t)rec * 128 + row) * 128 + dseg;
#pragma unroll
    for (int i = 0; i < 8; ++i) {
        bf16x8 v0 = *(const bf16x8*)(Oa + ob + i * 8);
        bf16x8 v1 = *(const bf16x8*)(p1 + i * 8);
        bf16x8 oo;
#pragma unroll
        for (int e = 0; e < 8; ++e)
            oo[e] = (short)f2bf(bf2f((unsigned short)v0[e]) * s0 +
                                bf2f((unsigned short)v1[e]) * s1);
        *(bf16x8*)(Oa + ob + i * 8) = oo;
    }
}

// ---------------- launch ----------------
extern "C" void kernel_launch(void* const* d_in, const int* in_sizes, int n_in,
                              void* d_out, int out_size, void* d_ws, size_t ws_size,
                              hipStream_t stream) {
    const float* X  = (const float*)d_in[0];
    const float* Wq = (const float*)d_in[1];
    const float* bq = (const float*)d_in[2];
    const float* Wk = (const float*)d_in[3];
    const float* bk = (const float*)d_in[4];
    const float* Wv = (const float*)d_in[5];
    const float* bv = (const float*)d_in[6];
    const float* Wo = (const float*)d_in[7];
    const float* bo = (const float*)d_in[8];
    float* out = (float*)d_out;

    if (ws_size < 80000000) return;
    char* ws = (char*)d_ws;
    unsigned short* Xb    = (unsigned short*)(ws);              // 16.78 MB; reused as AOb
    unsigned short* WqkvT = (unsigned short*)(ws + 16777216);   // [3072][2048] 12.58 MB
    unsigned short* WoT   = (unsigned short*)(ws + 29360128);   // 8.39 MB
    unsigned short* QKV   = (unsigned short*)(ws + 37748736);   // [4096][3072] 25.17 MB
    unsigned short* VbT   = (unsigned short*)(ws + 62914560);   // 4.19 MB
    unsigned short* part1 = (unsigned short*)(ws + 67108864);   // 256*128*128 bf16 = 8.39 MB
    float*          mlbuf = (float*)(ws + 75497472);            // 512*128*2 f32 = 512 KB
    float*          bqkv  = (float*)(ws + 76021760);            // 12 KB
    unsigned short* AOb   = Xb;                                 // Xb dead after QKV GEMM

    k_cvt_bf16<<<(B_ * S_ * H_ / 4 + 255) / 256, 256, 0, stream>>>(X, Xb, B_ * S_ * H_ / 4);
    k_transpose_qkv<<<dim3(HQKV / 32, H_ / 32), dim3(32, 8), 0, stream>>>(Wq, Wk, Wv, WqkvT);
    k_transpose_cvt<<<dim3(H_ / 32, H_ / 32), dim3(32, 8), 0, stream>>>(Wo, WoT, H_, H_);
    k_concat_bias<<<(HQKV + 255) / 256, 256, 0, stream>>>(bq, bk, bv, bqkv);

    // fused QKV projection: 256^2 8-phase, grid 16x12 = 192 blocks
    k_gemm256<true, true><<<dim3(16, 12), 512, 0, stream>>>(Xb, WqkvT, bqkv, QKV, 4096, HQKV, 2048);

    k_transpose_v<<<dim3(KV_ / 32, S_ / 32, B_), dim3(32, 8), 0, stream>>>(QKV, VbT);
    k_flash<<<dim3(768), 256, 0, stream>>>(QKV, VbT, AOb, part1, mlbuf);
    k_combine<<<dim3(256), 256, 0, stream>>>(mlbuf, part1, AOb);

    // O-projection: pipelined 128^2, 2D grid (no swizzle-overfetch)
    k_gemm128p<false, false><<<dim3(32, 16), 256, 0, stream>>>(AOb, WoT, bo, out, 4096, 2048, 2048);
}

// Round 11
// 216.987 us; speedup vs baseline: 1.0722x; 1.0722x over previous
//
#include <hip/hip_runtime.h>

// Problem constants
#define B_   2
#define S_   2048
#define H_   2048
#define NH_  16
#define G_   4
#define HD_  128
#define KV_  512
#define HQKV 3072   // fused Q|K|V output width

typedef __attribute__((ext_vector_type(8))) short bf16x8;
typedef __attribute__((ext_vector_type(4))) float f32x4;

__device__ __forceinline__ unsigned short f2bf(float f) {
    unsigned u = __float_as_uint(f);
    u += 0x7fff + ((u >> 16) & 1);   // RNE
    return (unsigned short)(u >> 16);
}
__device__ __forceinline__ float bf2f(unsigned short s) {
    return __uint_as_float(((unsigned)s) << 16);
}
// D.lo = bf16(a), D.hi = bf16(b)  (RNE)
__device__ __forceinline__ unsigned cvtpk(float a, float b) {
    unsigned r;
    asm volatile("v_cvt_pk_bf16_f32 %0, %1, %2" : "=v"(r) : "v"(a), "v"(b));
    return r;
}

#define GLDS16(gsrc, ldst)                                                            \
    __builtin_amdgcn_global_load_lds(                                                 \
        (const __attribute__((address_space(1))) void*)(gsrc),                        \
        (__attribute__((address_space(3))) void*)(ldst), 16, 0, 0)

// 1/sqrt(128) * log2(e): folded into Q columns of the QKV GEMM epilogue
#define SC2F (0.08838834764831843f * 1.4426950408889634f)

// ---------------- fp32 -> bf16 elementwise ----------------
__global__ void k_cvt_bf16(const float* __restrict__ in, unsigned short* __restrict__ out, int n4) {
    int i = blockIdx.x * blockDim.x + threadIdx.x;
    if (i >= n4) return;
    float4 v = ((const float4*)in)[i];
    ushort4 o;
    o.x = f2bf(v.x); o.y = f2bf(v.y); o.z = f2bf(v.z); o.w = f2bf(v.w);
    ((ushort4*)out)[i] = o;
}

// ---------------- fp32 [R][C] -> bf16 [C][R] (weight transpose+convert) ----------------
__global__ void k_transpose_cvt(const float* __restrict__ in, unsigned short* __restrict__ out,
                                int R, int C) {
    __shared__ float t[32][33];
    int c0 = blockIdx.x * 32, r0 = blockIdx.y * 32;
    int tx = threadIdx.x, ty = threadIdx.y;   // 32 x 8
#pragma unroll
    for (int i = 0; i < 4; ++i)
        t[ty + i*8][tx] = in[(size_t)(r0 + ty + i*8) * C + c0 + tx];
    __syncthreads();
#pragma unroll
    for (int i = 0; i < 4; ++i)
        out[(size_t)(c0 + ty + i*8) * R + r0 + tx] = f2bf(t[tx][ty + i*8]);
}

// ---------------- fused Wq|Wk|Wv transpose+convert -> WqkvT [3072][2048] ----------------
__global__ void k_transpose_qkv(const float* __restrict__ Wq, const float* __restrict__ Wk,
                                const float* __restrict__ Wv, unsigned short* __restrict__ out) {
    __shared__ float t[32][33];
    int n0g = blockIdx.x * 32;               // output row block (0..3071)
    int h0 = blockIdx.y * 32;                // input row block (0..2047)
    const float* src; int C, n0l;
    if (n0g < H_)            { src = Wq; C = H_;  n0l = n0g; }
    else if (n0g < H_ + KV_) { src = Wk; C = KV_; n0l = n0g - H_; }
    else                     { src = Wv; C = KV_; n0l = n0g - H_ - KV_; }
    int tx = threadIdx.x, ty = threadIdx.y;  // 32 x 8
#pragma unroll
    for (int i = 0; i < 4; ++i)
        t[ty + i*8][tx] = src[(size_t)(h0 + ty + i*8) * C + n0l + tx];
    __syncthreads();
#pragma unroll
    for (int i = 0; i < 4; ++i)
        out[(size_t)(n0g + ty + i*8) * H_ + h0 + tx] = f2bf(t[tx][ty + i*8]);
}

// ---------------- concat bq|bk|bv -> [3072] ----------------
__global__ void k_concat_bias(const float* __restrict__ bq, const float* __restrict__ bk,
                              const float* __restrict__ bv, float* __restrict__ out) {
    int i = blockIdx.x * 256 + threadIdx.x;
    if (i >= HQKV) return;
    out[i] = (i < H_) ? bq[i] : (i < H_ + KV_ ? bk[i - H_] : bv[i - H_ - KV_]);
}

// ---------------- V slice of QKV [B*S][3072] -> V^T [B][KV][S] ----------------
__global__ void k_transpose_v(const unsigned short* __restrict__ in, unsigned short* __restrict__ out) {
    __shared__ unsigned short t[32][33];
    int b = blockIdx.z;
    int c0 = blockIdx.x * 32, s0 = blockIdx.y * 32;
    int tx = threadIdx.x, ty = threadIdx.y;
#pragma unroll
    for (int i = 0; i < 4; ++i)
        t[ty + i*8][tx] = in[((size_t)b * S_ + s0 + ty + i*8) * HQKV + (H_ + KV_) + c0 + tx];
    __syncthreads();
#pragma unroll
    for (int i = 0; i < 4; ++i)
        out[((size_t)b * KV_ + c0 + ty + i*8) * S_ + s0 + tx] = t[tx][ty + i*8];
}

// ---------------- 256x256 8-phase bf16 GEMM (validated R9) ----------------
template <bool BF16OUT, bool QSCALE>
__global__ __launch_bounds__(512, 2) void k_gemm256(
    const unsigned short* __restrict__ A, const unsigned short* __restrict__ Bt,
    const float* __restrict__ bias, void* __restrict__ Cout, int M, int N, int K) {
    __shared__ __align__(16) unsigned short As[2][256 * 64];
    __shared__ __align__(16) unsigned short Bs[2][256 * 64];
    const int tid = threadIdx.x, lane = tid & 63;
    const int w = tid >> 6;
    const int l15 = lane & 15, l4 = lane >> 4;
    const int wr = w >> 2, wc = w & 3;        // 2 x 4 wave grid
    const int m0 = blockIdx.x * 256, n0 = blockIdx.y * 256;
    f32x4 acc[8][4] = {};

    auto stageA = [&](int buf, int kt, int h) {
#pragma unroll
        for (int i = 0; i < 2; ++i) {
            int p = i * 512 + tid;
            int j = p >> 3;
            int row = h * 64 + (j >> 6) * 128 + (j & 63);
            int sc = p & 7;
            int c = sc ^ (row & 7);
            GLDS16(A + (size_t)(m0 + row) * K + kt * 64 + c * 8,
                   &As[buf][(row * 8 + sc) * 8]);
        }
    };
    auto stageB = [&](int buf, int kt, int h) {
#pragma unroll
        for (int i = 0; i < 2; ++i) {
            int p = i * 512 + tid;
            int j = p >> 3;
            int row = h * 32 + (j >> 5) * 64 + (j & 31);
            int sc = p & 7;
            int c = sc ^ (row & 7);
            GLDS16(Bt + (size_t)(n0 + row) * K + kt * 64 + c * 8,
                   &Bs[buf][(row * 8 + sc) * 8]);
        }
    };

    const int NT = K >> 6;
    stageB(0, 0, 0); stageA(0, 0, 0); stageB(0, 0, 1); stageA(0, 0, 1);
    stageB(1, 1, 0); stageA(1, 1, 0);

    bf16x8 bf[2][2];
    for (int t = 0; t < NT; ++t) {
        const int cur = t & 1, nxt = cur ^ 1;
        if (t == NT - 1) { asm volatile("s_waitcnt vmcnt(0)" ::: "memory"); }
        else             { asm volatile("s_waitcnt vmcnt(4)" ::: "memory"); }
        __builtin_amdgcn_s_barrier();
        __builtin_amdgcn_sched_barrier(0);

#pragma unroll
        for (int q = 0; q < 4; ++q) {
            const int nh = q >> 1, mh = q & 1;
            bf16x8 af[4][2];
#pragma unroll
            for (int mf2 = 0; mf2 < 4; ++mf2)
#pragma unroll
                for (int ks = 0; ks < 2; ++ks) {
                    int row = wr * 128 + (mh * 4 + mf2) * 16 + l15;
                    int ch = (ks * 4 + l4) ^ (row & 7);
                    af[mf2][ks] = *(const bf16x8*)(&As[cur][(row * 8 + ch) * 8]);
                }
            if (mh == 0) {
#pragma unroll
                for (int nf2 = 0; nf2 < 2; ++nf2)
#pragma unroll
                    for (int ks = 0; ks < 2; ++ks) {
                        int row = wc * 64 + (nh * 2 + nf2) * 16 + l15;
                        int ch = (ks * 4 + l4) ^ (row & 7);
                        bf[nf2][ks] = *(const bf16x8*)(&Bs[cur][(row * 8 + ch) * 8]);
                    }
            }
            if (q == 0)      { if (t + 1 < NT) stageB(nxt, t + 1, 1); }
            else if (q == 1) { if (t + 1 < NT) stageA(nxt, t + 1, 1); }
            else if (q == 2) { if (t + 2 < NT) stageB(cur, t + 2, 0); }
            else             { if (t + 2 < NT) stageA(cur, t + 2, 0); }

            __builtin_amdgcn_sched_barrier(0);
            __builtin_amdgcn_s_barrier();
            asm volatile("s_waitcnt lgkmcnt(0)" ::: "memory");
            __builtin_amdgcn_sched_barrier(0);
            __builtin_amdgcn_s_setprio(1);
#pragma unroll
            for (int mf2 = 0; mf2 < 4; ++mf2)
#pragma unroll
                for (int nf2 = 0; nf2 < 2; ++nf2)
#pragma unroll
                    for (int ks = 0; ks < 2; ++ks)
                        acc[mh * 4 + mf2][nh * 2 + nf2] = __builtin_amdgcn_mfma_f32_16x16x32_bf16(
                            af[mf2][ks], bf[nf2][ks], acc[mh * 4 + mf2][nh * 2 + nf2], 0, 0, 0);
            __builtin_amdgcn_s_setprio(0);
            __builtin_amdgcn_s_barrier();
        }
    }

#pragma unroll
    for (int mf = 0; mf < 8; ++mf) {
        int row = m0 + wr * 128 + mf * 16 + l4 * 4;
#pragma unroll
        for (int nf = 0; nf < 4; ++nf) {
            int col = n0 + wc * 64 + nf * 16 + l15;
            float bv = bias[col];
#pragma unroll
            for (int r = 0; r < 4; ++r) {
                float v = acc[mf][nf][r] + bv;
                if (QSCALE) { if (col < H_) v *= SC2F; }
                if (BF16OUT)
                    ((unsigned short*)Cout)[(size_t)(row + r) * N + col] = f2bf(v);
                else
                    ((float*)Cout)[(size_t)(row + r) * N + col] = v;
            }
        }
    }
}

// ---------------- 256x128 8-phase bf16 GEMM (full-chip O-proj variant) ----------------
// 8 waves (2x4), per-wave C = 128x32, acc[8][2]. B-stripes at BIT4 granularity so each
// stage target equals the nh-phase read set across all waves (bit5 would race at BN=128).
// stageB = 1 GLDS/thread, stageA = 2. Ledger: prologue 9 in flight; tile-top vmcnt(3)
// retires the current tile's 6; last tile vmcnt(0). LDS 96 KB.
template <bool BF16OUT>
__global__ __launch_bounds__(512, 1) void k_gemm256x128(
    const unsigned short* __restrict__ A, const unsigned short* __restrict__ Bt,
    const float* __restrict__ bias, void* __restrict__ Cout, int M, int N, int K) {
    __shared__ __align__(16) unsigned short As[2][256 * 64];
    __shared__ __align__(16) unsigned short Bs[2][128 * 64];
    const int tid = threadIdx.x, lane = tid & 63;
    const int w = tid >> 6;
    const int l15 = lane & 15, l4 = lane >> 4;
    const int wr = w >> 2, wc = w & 3;        // 2 x 4 wave grid
    const int m0 = blockIdx.x * 256, n0 = blockIdx.y * 128;
    f32x4 acc[8][2] = {};

    auto stageA = [&](int buf, int kt, int h) {
#pragma unroll
        for (int i = 0; i < 2; ++i) {
            int p = i * 512 + tid;
            int j = p >> 3;
            int row = h * 64 + (j >> 6) * 128 + (j & 63);
            int sc = p & 7;
            int c = sc ^ (row & 7);
            GLDS16(A + (size_t)(m0 + row) * K + kt * 64 + c * 8,
                   &As[buf][(row * 8 + sc) * 8]);
        }
    };
    auto stageB = [&](int buf, int kt, int h) {
        int j = tid >> 3;                     // 0..63
        int row = h * 16 + (j >> 4) * 32 + (j & 15);   // stripe: bit4 == h
        int sc = tid & 7;
        int c = sc ^ (row & 7);
        GLDS16(Bt + (size_t)(n0 + row) * K + kt * 64 + c * 8,
               &Bs[buf][(row * 8 + sc) * 8]);
    };

    const int NT = K >> 6;
    stageB(0, 0, 0); stageA(0, 0, 0); stageB(0, 0, 1); stageA(0, 0, 1);
    stageB(1, 1, 0); stageA(1, 1, 0);

    bf16x8 bf[2];
    for (int t = 0; t < NT; ++t) {
        const int cur = t & 1, nxt = cur ^ 1;
        if (t == NT - 1) { asm volatile("s_waitcnt vmcnt(0)" ::: "memory"); }
        else             { asm volatile("s_waitcnt vmcnt(3)" ::: "memory"); }
        __builtin_amdgcn_s_barrier();
        __builtin_amdgcn_sched_barrier(0);

#pragma unroll
        for (int q = 0; q < 4; ++q) {
            const int nh = q >> 1, mh = q & 1;
            bf16x8 af[4][2];
#pragma unroll
            for (int mf2 = 0; mf2 < 4; ++mf2)
#pragma unroll
                for (int ks = 0; ks < 2; ++ks) {
                    int row = wr * 128 + (mh * 4 + mf2) * 16 + l15;
                    int ch = (ks * 4 + l4) ^ (row & 7);
                    af[mf2][ks] = *(const bf16x8*)(&As[cur][(row * 8 + ch) * 8]);
                }
            if (mh == 0) {
#pragma unroll
                for (int ks = 0; ks < 2; ++ks) {
                    int row = wc * 32 + nh * 16 + l15;
                    int ch = (ks * 4 + l4) ^ (row & 7);
                    bf[ks] = *(const bf16x8*)(&Bs[cur][(row * 8 + ch) * 8]);
                }
            }
            if (q == 0)      { if (t + 1 < NT) stageB(nxt, t + 1, 1); }
            else if (q == 1) { if (t + 1 < NT) stageA(nxt, t + 1, 1); }
            else if (q == 2) { if (t + 2 < NT) stageB(cur, t + 2, 0); }
            else             { if (t + 2 < NT) stageA(cur, t + 2, 0); }

            __builtin_amdgcn_sched_barrier(0);
            __builtin_amdgcn_s_barrier();
            asm volatile("s_waitcnt lgkmcnt(0)" ::: "memory");
            __builtin_amdgcn_sched_barrier(0);
            __builtin_amdgcn_s_setprio(1);
#pragma unroll
            for (int mf2 = 0; mf2 < 4; ++mf2)
#pragma unroll
                for (int ks = 0; ks < 2; ++ks)
                    acc[mh * 4 + mf2][nh] = __builtin_amdgcn_mfma_f32_16x16x32_bf16(
                        af[mf2][ks], bf[ks], acc[mh * 4 + mf2][nh], 0, 0, 0);
            __builtin_amdgcn_s_setprio(0);
            __builtin_amdgcn_s_barrier();
        }
    }

#pragma unroll
    for (int mf = 0; mf < 8; ++mf) {
        int row = m0 + wr * 128 + mf * 16 + l4 * 4;
#pragma unroll
        for (int nf = 0; nf < 2; ++nf) {
            int col = n0 + wc * 32 + nf * 16 + l15;
            float bv = bias[col];
#pragma unroll
            for (int r = 0; r < 4; ++r) {
                float v = acc[mf][nf][r] + bv;
                if (BF16OUT)
                    ((unsigned short*)Cout)[(size_t)(row + r) * N + col] = f2bf(v);
                else
                    ((float*)Cout)[(size_t)(row + r) * N + col] = v;
            }
        }
    }
}

// ---------------- causal GQA flash attention (R9-proven): QBLK=64, swapped-QK ----------------
__global__ __launch_bounds__(256, 4) void k_flash(
    const unsigned short* __restrict__ QKV,  // [B*S][3072]  Q|K|V  (Q pre-scaled)
    const unsigned short* __restrict__ VT,   // [B][KV][S]
    unsigned short* __restrict__ Oa,         // [B*S][H]
    unsigned short* __restrict__ part1,      // [512][64][128] bf16 chunk1 partial O
    float* __restrict__ mlbuf) {             // [1024][64][2] f32 (m,l) per chunk
    __shared__ __align__(16) unsigned short Ks[64 * 128];    // K tile, chunk-swizzled
    __shared__ __align__(16) unsigned short Vs[128 * 64];    // V^T tile, chunk-swizzled
    const int tid = threadIdx.x, lane = tid & 63, w = tid >> 6;
    const int l15 = lane & 15, l4 = lane >> 4;
    const int bid = blockIdx.x;               // 0..1535
    const int xcd = bid & 7, idx = bid >> 3;  // 192 jobs per XCD
    const int bh = xcd * 4 + (idx & 3);       // 4 heads per XCD = one (b,g)
    const int jidx = idx >> 2;                // 0..47, descending work
    const int b = bh >> 4, nh = bh & 15, g = nh >> 2;

    int qt, t0, t1, mode;                     // mode: 0 full, 1 chunk0, 2 chunk1
    if (jidx < 16) { qt = 16 + jidx; t0 = 0; t1 = 16; mode = 1; }
    else {
        int k = jidx - 16, j = k >> 1;
        if ((k & 1) == 0) { qt = 31 - j; t0 = 16; t1 = qt + 1; mode = 2; }
        else              { qt = 15 - j; t0 = 0;  t1 = qt + 1; mode = 0; }
    }
    const int qbase = qt * 64 + w * 16;       // wave's 16 q-rows; lane's q = qbase + l15

    const unsigned short* kgbase = QKV + (size_t)b * S_ * HQKV + H_ + g * HD_;
    const unsigned short* vgbase = VT + ((size_t)b * KV_ + g * HD_) * S_;

    auto issueK = [&](int kt) {
        const int kv0 = kt * 64;
#pragma unroll
        for (int i = 0; i < 4; ++i) {
            int p = i * 256 + tid;
            int row = p >> 4, c = (p & 15) ^ (row & 15);
            GLDS16(kgbase + (size_t)(kv0 + row) * HQKV + c * 8, &Ks[(i * 256 + w * 64) * 8]);
        }
    };
    auto issueV = [&](int kt) {
        const int kv0 = kt * 64;
#pragma unroll
        for (int i = 0; i < 4; ++i) {
            int p = i * 256 + tid;
            int row = p >> 3, c = (p & 7) ^ (row & 7);
            GLDS16(vgbase + (size_t)row * S_ + kv0 + c * 8, &Vs[(i * 256 + w * 64) * 8]);
        }
    };

    bf16x8 qf[4];
#pragma unroll
    for (int kb = 0; kb < 4; ++kb)
        qf[kb] = *(const bf16x8*)(QKV + (size_t)(b * S_ + qbase + l15) * HQKV +
                                  nh * HD_ + kb * 32 + l4 * 8);

    f32x4 o[8] = {};                          // O^T: o[nc][r] = O[d=nc*16+l4*4+r][q=l15]
    float m_r = -1e30f, l_r = 0.f;

    const int src0 = l15 + 16 * ((2 * l4) & 3);
    const int src1 = l15 + 16 * ((2 * l4 + 1) & 3);
    const bool hsel = ((l4 >> 1) & 1) != 0;

    issueK(t0);
    issueV(t0);

    for (int kt = t0; kt < t1; ++kt) {
        const int kv0 = kt * 64;
        asm volatile("s_waitcnt vmcnt(4)" ::: "memory");
        __builtin_amdgcn_s_barrier();
        __builtin_amdgcn_sched_barrier(0);

        // S^T = K Q^T
        f32x4 s[4] = {};
#pragma unroll
        for (int kb = 0; kb < 4; ++kb) {
            bf16x8 kf[4];
#pragma unroll
            for (int n = 0; n < 4; ++n) {
                int row = n * 16 + l15;
                int sl = (kb * 4 + l4) ^ (row & 15);
                kf[n] = *(const bf16x8*)(&Ks[(row * 16 + sl) * 8]);
            }
            __builtin_amdgcn_s_setprio(1);
#pragma unroll
            for (int n = 0; n < 4; ++n)
                s[n] = __builtin_amdgcn_mfma_f32_16x16x32_bf16(kf[n], qf[kb], s[n], 0, 0, 0);
            __builtin_amdgcn_s_setprio(0);
        }
        if (kv0 + 63 > qbase) {
            const int qrow = qbase + l15;
#pragma unroll
            for (int n = 0; n < 4; ++n)
#pragma unroll
                for (int r = 0; r < 4; ++r) {
                    int kcol = kv0 + n * 16 + l4 * 4 + r;
                    if (kcol > qrow) s[n][r] = -1e30f;
                }
        }
        float pmax = s[0][0];
#pragma unroll
        for (int n = 0; n < 4; ++n)
#pragma unroll
            for (int r = 0; r < 4; ++r) pmax = fmaxf(pmax, s[n][r]);
        pmax = fmaxf(pmax, __shfl_xor(pmax, 16));
        pmax = fmaxf(pmax, __shfl_xor(pmax, 32));
        if (__any(pmax > m_r + 8.0f)) {
            float mn = fmaxf(m_r, pmax);
            float sf = exp2f(m_r - mn);
            m_r = mn;
            l_r *= sf;
#pragma unroll
            for (int nc = 0; nc < 8; ++nc) {
                f32x4 t = o[nc];
                t[0] *= sf; t[1] *= sf; t[2] *= sf; t[3] *= sf;
                o[nc] = t;
            }
        }
        float rsum = 0.f;
#pragma unroll
        for (int n = 0; n < 4; ++n)
#pragma unroll
            for (int r = 0; r < 4; ++r) {
                float p = exp2f(s[n][r] - m_r);
                s[n][r] = p;
                rsum += p;
            }
        rsum += __shfl_xor(rsum, 16);
        rsum += __shfl_xor(rsum, 32);
        l_r += rsum;

        unsigned plo[4], phi[4];
#pragma unroll
        for (int n = 0; n < 4; ++n) {
            plo[n] = cvtpk(s[n][0], s[n][1]);
            phi[n] = cvtpk(s[n][2], s[n][3]);
        }

        asm volatile("s_waitcnt vmcnt(0)" ::: "memory");
        __builtin_amdgcn_s_barrier();
        __builtin_amdgcn_sched_barrier(0);
        if (kt + 1 < t1) issueK(kt + 1);

#pragma unroll
        for (int kb = 0; kb < 2; ++kb) {
            const int n0i = 2 * kb, n1i = 2 * kb + 1;
            unsigned a0, a1, w0, w1, w2, w3;
            a0 = __shfl((int)plo[n0i], src0); a1 = __shfl((int)plo[n1i], src0); w0 = hsel ? a1 : a0;
            a0 = __shfl((int)phi[n0i], src0); a1 = __shfl((int)phi[n1i], src0); w1 = hsel ? a1 : a0;
            a0 = __shfl((int)plo[n0i], src1); a1 = __shfl((int)plo[n1i], src1); w2 = hsel ? a1 : a0;
            a0 = __shfl((int)phi[n0i], src1); a1 = __shfl((int)phi[n1i], src1); w3 = hsel ? a1 : a0;
            int4 pw = make_int4((int)w0, (int)w1, (int)w2, (int)w3);
            bf16x8 pf = *(bf16x8*)&pw;
            __builtin_amdgcn_s_setprio(1);
#pragma unroll
            for (int nc = 0; nc < 8; ++nc) {
                int row = nc * 16 + l15;
                int sl = (kb * 4 + l4) ^ (row & 7);
                bf16x8 vf = *(const bf16x8*)(&Vs[(row * 8 + sl) * 8]);
                o[nc] = __builtin_amdgcn_mfma_f32_16x16x32_bf16(vf, pf, o[nc], 0, 0, 0);
            }
            __builtin_amdgcn_s_setprio(0);
        }

        __builtin_amdgcn_s_barrier();
        __builtin_amdgcn_sched_barrier(0);
        if (kt + 1 < t1) issueV(kt + 1);
    }

    const int qrow = qbase + l15;
    if (mode == 0) {
        float inv = 1.0f / l_r;
        size_t base = (size_t)(b * S_ + qrow) * H_ + nh * HD_ + l4 * 4;
#pragma unroll
        for (int nc = 0; nc < 8; ++nc) {
            uint2 pk;
            pk.x = cvtpk(o[nc][0] * inv, o[nc][1] * inv);
            pk.y = cvtpk(o[nc][2] * inv, o[nc][3] * inv);
            *(uint2*)(Oa + base + nc * 16) = pk;
        }
    } else {
        const int base = bh * 16 + (qt - 16);
        const int c = (mode == 1) ? 0 : 1;
        float* mlrec = mlbuf + (size_t)(base * 2 + c) * 64 * 2;
        if (l4 == 0) {
            int row = w * 16 + l15;
            mlrec[row * 2 + 0] = m_r;
            mlrec[row * 2 + 1] = l_r;
        }
        if (mode == 1) {
            size_t ob = (size_t)(b * S_ + qrow) * H_ + nh * HD_ + l4 * 4;
#pragma unroll
            for (int nc = 0; nc < 8; ++nc) {
                uint2 pk;
                pk.x = cvtpk(o[nc][0], o[nc][1]);
                pk.y = cvtpk(o[nc][2], o[nc][3]);
                *(uint2*)(Oa + ob + nc * 16) = pk;
            }
        } else {
            size_t pb = ((size_t)base * 64 + w * 16 + l15) * 128 + l4 * 4;
#pragma unroll
            for (int nc = 0; nc < 8; ++nc) {
                uint2 pk;
                pk.x = cvtpk(o[nc][0], o[nc][1]);
                pk.y = cvtpk(o[nc][2], o[nc][3]);
                *(uint2*)(part1 + pb + nc * 16) = pk;
            }
        }
    }
}

// ---------------- combine split-K partials ----------------
__global__ __launch_bounds__(256) void k_combine(
    const float* __restrict__ mlbuf, const unsigned short* __restrict__ part1,
    unsigned short* __restrict__ Oa) {
    int rec = blockIdx.x;                 // 0..511: bh*16 + (qt-16)
    int bh = rec >> 4, qt = 16 + (rec & 15);
    int b = bh >> 4, nh = bh & 15;
    int row = threadIdx.x >> 2;           // 0..63
    int dseg = (threadIdx.x & 3) * 32;
    const float* ml0 = mlbuf + (size_t)(rec * 2 + 0) * 128;
    const float* ml1 = mlbuf + (size_t)(rec * 2 + 1) * 128;
    float m0 = ml0[row * 2], l0 = ml0[row * 2 + 1];
    float m1 = ml1[row * 2], l1 = ml1[row * 2 + 1];
    float M = fmaxf(m0, m1);
    float a0 = exp2f(m0 - M), a1 = exp2f(m1 - M);
    float L = a0 * l0 + a1 * l1;
    float s0 = a0 / L, s1 = a1 / L;
    size_t ob = ((size_t)(b * S_) + qt * 64 + row) * H_ + nh * HD_ + dseg;
    const unsigned short* p1 = part1 + ((size_t)rec * 64 + row) * 128 + dseg;
#pragma unroll
    for (int i = 0; i < 4; ++i) {
        bf16x8 v0 = *(const bf16x8*)(Oa + ob + i * 8);
        bf16x8 v1 = *(const bf16x8*)(p1 + i * 8);
        bf16x8 oo;
#pragma unroll
        for (int e = 0; e < 8; ++e)
            oo[e] = (short)f2bf(bf2f((unsigned short)v0[e]) * s0 +
                                bf2f((unsigned short)v1[e]) * s1);
        *(bf16x8*)(Oa + ob + i * 8) = oo;
    }
}

// ---------------- launch ----------------
extern "C" void kernel_launch(void* const* d_in, const int* in_sizes, int n_in,
                              void* d_out, int out_size, void* d_ws, size_t ws_size,
                              hipStream_t stream) {
    const float* X  = (const float*)d_in[0];
    const float* Wq = (const float*)d_in[1];
    const float* bq = (const float*)d_in[2];
    const float* Wk = (const float*)d_in[3];
    const float* bk = (const float*)d_in[4];
    const float* Wv = (const float*)d_in[5];
    const float* bv = (const float*)d_in[6];
    const float* Wo = (const float*)d_in[7];
    const float* bo = (const float*)d_in[8];
    float* out = (float*)d_out;

    if (ws_size < 80000000) return;
    char* ws = (char*)d_ws;
    unsigned short* Xb    = (unsigned short*)(ws);              // 16.78 MB; reused as AOb
    unsigned short* WqkvT = (unsigned short*)(ws + 16777216);   // [3072][2048] 12.58 MB
    unsigned short* WoT   = (unsigned short*)(ws + 29360128);   // 8.39 MB
    unsigned short* QKV   = (unsigned short*)(ws + 37748736);   // [4096][3072] 25.17 MB
    unsigned short* VbT   = (unsigned short*)(ws + 62914560);   // 4.19 MB
    unsigned short* part1 = (unsigned short*)(ws + 67108864);   // 512*64*128 bf16 = 8.39 MB
    float*          mlbuf = (float*)(ws + 75497472);            // 1024*64*2 f32 = 512 KB
    float*          bqkv  = (float*)(ws + 76021760);            // 12 KB
    unsigned short* AOb   = Xb;                                 // Xb dead after QKV GEMM

    k_cvt_bf16<<<(B_ * S_ * H_ / 4 + 255) / 256, 256, 0, stream>>>(X, Xb, B_ * S_ * H_ / 4);
    k_transpose_qkv<<<dim3(HQKV / 32, H_ / 32), dim3(32, 8), 0, stream>>>(Wq, Wk, Wv, WqkvT);
    k_transpose_cvt<<<dim3(H_ / 32, H_ / 32), dim3(32, 8), 0, stream>>>(Wo, WoT, H_, H_);
    k_concat_bias<<<(HQKV + 255) / 256, 256, 0, stream>>>(bq, bk, bv, bqkv);

    // fused QKV projection: 256^2 8-phase, grid 16x12 = 192 blocks
    k_gemm256<true, true><<<dim3(16, 12), 512, 0, stream>>>(Xb, WqkvT, bqkv, QKV, 4096, HQKV, 2048);

    k_transpose_v<<<dim3(KV_ / 32, S_ / 32, B_), dim3(32, 8), 0, stream>>>(QKV, VbT);
    k_flash<<<dim3(1536), 256, 0, stream>>>(QKV, VbT, AOb, part1, mlbuf);
    k_combine<<<dim3(512), 256, 0, stream>>>(mlbuf, part1, AOb);

    // O-projection: 256x128 8-phase, grid 16x16 = 256 blocks (full chip)
    k_gemm256x128<false><<<dim3(16, 16), 512, 0, stream>>>(AOb, WoT, bo, out, 4096, 2048, 2048);
}